// Round 4
// baseline (235.753 us; speedup 1.0000x reference)
//
#include <hip/hip_runtime.h>

#define S_LEN 512
#define B_DIM 1024
#define T_DIM 48
#define NPAIR 24
#define L2E 1.4426950408889634f
#define LN2 0.6931471805599453f

// v_exp_f32 computes 2^x ; v_log_f32 computes log2(x)
#define EXP2F(x) __builtin_amdgcn_exp2f(x)
#define LOG2F(x) __builtin_amdgcn_logf(x)

typedef _Float16 h2 __attribute__((ext_vector_type(2)));
typedef __fp16   r2 __attribute__((ext_vector_type(2)));

// pack two f32 -> f16 pair (v_cvt_pkrtz_f16_f32), returned as arithmetic _Float16x2
__device__ __forceinline__ h2 pkrtz(float a, float b) {
  r2 t = __builtin_amdgcn_cvt_pkrtz(a, b);
  return __builtin_bit_cast(h2, t);
}

// broadcast the 32-bit pair held by `lane` to all lanes (readlane -> SGPR)
__device__ __forceinline__ h2 bpick(h2 src, int lane) {
  int s = __builtin_amdgcn_readlane(__builtin_bit_cast(int, src), lane);
  return __builtin_bit_cast(h2, s);
}

// ---- DPP wave-64 reduction helpers (full result valid in lane 63) ----
template <int CTRL, int RMASK>
__device__ __forceinline__ float dppmovf(float v) {
  return __int_as_float(__builtin_amdgcn_update_dpp(
      __float_as_int(v), __float_as_int(v), CTRL, RMASK, 0xF, false));
}
template <int CTRL, int RMASK>
__device__ __forceinline__ float dppmaxf(float m) {
  return fmaxf(m, dppmovf<CTRL, RMASK>(m));
}
template <int CTRL, int RMASK>
__device__ __forceinline__ float dppaddf(float m) {
  return m + dppmovf<CTRL, RMASK>(m);
}

__device__ __forceinline__ float wave_max63(float m) {
  m = dppmaxf<0xB1, 0xF>(m);   // quad_perm [1,0,3,2] : xor 1
  m = dppmaxf<0x4E, 0xF>(m);   // quad_perm [2,3,0,1] : xor 2
  m = dppmaxf<0x141, 0xF>(m);  // row_half_mirror     : xor 4
  m = dppmaxf<0x140, 0xF>(m);  // row_mirror          : xor 8
  m = dppmaxf<0x142, 0xA>(m);  // row_bcast15 -> rows 1,3
  m = dppmaxf<0x143, 0xC>(m);  // row_bcast31 -> rows 2,3 ; lane63 = full max
  return __int_as_float(__builtin_amdgcn_readlane(__float_as_int(m), 63));
}
__device__ __forceinline__ float wave_sum63(float m) {
  m = dppaddf<0xB1, 0xF>(m);
  m = dppaddf<0x4E, 0xF>(m);
  m = dppaddf<0x141, 0xF>(m);
  m = dppaddf<0x140, 0xF>(m);
  m = dppaddf<0x142, 0xA>(m);
  m = dppaddf<0x143, 0xC>(m);  // lane63 = full sum
  return __int_as_float(__builtin_amdgcn_readlane(__float_as_int(m), 63));
}

// ---- main scan: blocks 0..1023 = forward(LSE) chain, 1024..2047 = viterbi(max) chain.
// One wave per chain; lane = tag index, lanes >= 48 clone lane 47.
__global__ __launch_bounds__(64)
void crf_scan(const float* __restrict__ em, const float* __restrict__ mask,
              const float* __restrict__ trans, const float* __restrict__ startT,
              const float* __restrict__ stopT, float* __restrict__ out)
{
  const int b    = blockIdx.x & (B_DIM - 1);
  const int mode = blockIdx.x >> 10;   // 0 = fv, 1 = vv  (b and b+1024 -> same XCD)
  const int i    = threadIdx.x;
  const int ri   = (i < T_DIM) ? i : (T_DIM - 1);

  // rebased state: true value = OFF + v
  float v   = startT[ri] + em[(size_t)b * T_DIM + ri];
  float OFF = 0.f;

  const float* emb = em + (size_t)b * T_DIM + ri;
  const size_t estep = (size_t)B_DIM * T_DIM;
  float e1 = emb[1 * estep];
  float e2 = emb[2 * estep];
  float e3 = emb[3 * estep];
  float mk = mask[B_DIM + b];

  if (mode == 0) {
    // per-lane row ri of exp(trans), packed f16 over j-pairs
    h2 Epk[NPAIR];
#pragma unroll
    for (int k = 0; k < NPAIR; ++k)
      Epk[k] = pkrtz(EXP2F(trans[ri * T_DIM + 2 * k]     * L2E),
                     EXP2F(trans[ri * T_DIM + 2 * k + 1] * L2E));

    for (int s = 1; s < S_LEN; ++s) {
      int sp = (s + 3 < S_LEN) ? s + 3 : S_LEN - 1;
      float ep  = emb[(size_t)sp * estep];
      int sn = (s + 1 < S_LEN) ? s + 1 : S_LEN - 1;
      float mkn = mask[sn * B_DIM + b];

      float mf = wave_max63(v);
      float p  = EXP2F((v - mf) * L2E);              // p in [0,1]
      h2 pp = pkrtz(p, dppmovf<0xB1, 0xF>(p));       // even lanes: (p_2k, p_2k+1)

      h2 a0{}, a1{}, a2{}, a3{};                     // 4 independent f16 FMA chains
#pragma unroll
      for (int k = 0; k < 6; ++k) {
        a0 += bpick(pp, 2 * k)        * Epk[k];
        a1 += bpick(pp, 2 * (k + 6))  * Epk[k + 6];
        a2 += bpick(pp, 2 * (k + 12)) * Epk[k + 12];
        a3 += bpick(pp, 2 * (k + 18)) * Epk[k + 18];
      }
      a0 += a1; a2 += a3; a0 += a2;
      float accF = (float)a0.x + (float)a0.y;        // sum_j p_j * exp(t_ij)

      float fnew = fmaf(LN2, LOG2F(fmaxf(accF, 1e-30f)), e1);
      float fold = v - mf;
      v = fmaf(mk, fnew - fold, fold);
      OFF += mf;

      e1 = e2; e2 = e3; e3 = ep; mk = mkn;
    }
    float q  = v + stopT[ri];
    float mq = wave_max63(q);
    float e  = EXP2F((q - mq) * L2E);
    e = (i < T_DIM) ? e : 0.f;                       // zero clone lanes for the sum
    float alpha = OFF + mq + LN2 * LOG2F(wave_sum63(e));
    if (i == 0) out[1 + B_DIM + b] = alpha;
  } else {
    h2 Tpk[NPAIR];
#pragma unroll
    for (int k = 0; k < NPAIR; ++k)
      Tpk[k] = pkrtz(trans[ri * T_DIM + 2 * k], trans[ri * T_DIM + 2 * k + 1]);

    const h2 NEG = {(_Float16)-60000.f, (_Float16)-60000.f};
    for (int s = 1; s < S_LEN; ++s) {
      int sp = (s + 3 < S_LEN) ? s + 3 : S_LEN - 1;
      float ep  = emb[(size_t)sp * estep];
      int sn = (s + 1 < S_LEN) ? s + 1 : S_LEN - 1;
      float mkn = mask[sn * B_DIM + b];

      float mv = wave_max63(v);
      float vr = v - mv;                             // <= 0, f16-safe
      h2 vp = pkrtz(vr, dppmovf<0xB1, 0xF>(vr));

      h2 m0 = NEG, m1 = NEG;                         // 2 independent max chains
#pragma unroll
      for (int k = 0; k < 12; ++k) {
        m0 = __builtin_elementwise_max(m0, bpick(vp, 2 * k)        + Tpk[k]);
        m1 = __builtin_elementwise_max(m1, bpick(vp, 2 * (k + 12)) + Tpk[k + 12]);
      }
      m0 = __builtin_elementwise_max(m0, m1);
      float mx = fmaxf((float)m0.x, (float)m0.y);    // max_j (vr_j + t_ij)

      float vnew = e1 + mx;
      float vold = v - mv;
      v = fmaf(mk, vnew - vold, vold);
      OFF += mv;

      e1 = e2; e2 = e3; e3 = ep; mk = mkn;
    }
    float best = OFF + wave_max63(v + stopT[ri]);
    if (i == 0) out[1 + 2 * B_DIM + b] = best;
  }
}

// ---- real-path score: one block per b, deterministic LDS tree reduction ----
__global__ __launch_bounds__(256)
void crf_real(const float* __restrict__ em, const int* __restrict__ tags,
              const float* __restrict__ mask, const float* __restrict__ trans,
              const float* __restrict__ startT, const float* __restrict__ stopT,
              float* __restrict__ out)
{
  __shared__ float red[256];
  const int b = blockIdx.x;
  const int t = threadIdx.x;
  float acc = 0.f;
  for (int s = 1 + t; s < S_LEN; s += 256) {
    int   tp  = tags[(s - 1) * B_DIM + b];
    int   tc  = tags[s * B_DIM + b];
    float mkv = mask[s * B_DIM + b];
    float emt = em[((size_t)s * B_DIM + b) * T_DIM + tc];
    acc = fmaf(mkv, trans[tp * T_DIM + tc] + emt, acc);
  }
  red[t] = acc;
  __syncthreads();
  for (int w = 128; w > 0; w >>= 1) {
    if (t < w) red[t] += red[t + w];
    __syncthreads();
  }
  if (t == 0)
    out[1 + b] = startT[tags[b]] + stopT[tags[(S_LEN - 1) * B_DIM + b]] + red[0];
}

// ---- loss = mean(alpha - real) ----
__global__ __launch_bounds__(256)
void crf_loss(float* __restrict__ out)
{
  __shared__ float red[256];
  int t = threadIdx.x;
  float a = 0.f;
  for (int b = t; b < B_DIM; b += 256)
    a += out[1 + B_DIM + b] - out[1 + b];
  red[t] = a;
  __syncthreads();
  for (int w = 128; w > 0; w >>= 1) {
    if (t < w) red[t] += red[t + w];
    __syncthreads();
  }
  if (t == 0) out[0] = red[0] * (1.0f / B_DIM);
}

extern "C" void kernel_launch(void* const* d_in, const int* in_sizes, int n_in,
                              void* d_out, int out_size, void* d_ws, size_t ws_size,
                              hipStream_t stream) {
  (void)in_sizes; (void)n_in; (void)d_ws; (void)ws_size; (void)out_size;
  const float* em     = (const float*)d_in[0];
  const int*   tags   = (const int*)d_in[1];
  const float* mask   = (const float*)d_in[2];
  const float* trans  = (const float*)d_in[3];
  const float* startT = (const float*)d_in[4];
  const float* stopT  = (const float*)d_in[5];
  float* out = (float*)d_out;

  hipLaunchKernelGGL(crf_scan, dim3(2 * B_DIM), dim3(64), 0, stream,
                     em, mask, trans, startT, stopT, out);
  hipLaunchKernelGGL(crf_real, dim3(B_DIM), dim3(256), 0, stream,
                     em, tags, mask, trans, startT, stopT, out);
  hipLaunchKernelGGL(crf_loss, dim3(1), dim3(256), 0, stream, out);
}